// Round 1
// baseline (94.036 us; speedup 1.0000x reference)
//
#include <hip/hip_runtime.h>

// out[b,n] = 1/(16*50625) * sum_j Acoeff[n,j] * S[b,j]
// S[b,j]   = BM[j] . T[b,j],  BM = Bbasis @ M   (hoisted: B.(M.T) == (B@M).T)
// T[b,j,m] = sum_{p,q,r,s} w[j1][p] w[j2][q] w[j3][r] w[j4][s] * arr[b,p,q,r,s,m]
// w masks (per dim, D=16, L=3, window R=2, stride 1, VALID):
//   class0: 0x36DB  class1: 0x6DB6  class2: 0xDB6C
//
// Structure (3 dispatches, no atomics, no memset):
//   stage0 <<<1,256>>>   : BM = Bbasis @ M  (81x32, into ws)
//   stage1 <<<1024,128>>>: per (b,p,q) tile -> s-reduce -> r-reduce -> 81 dots
//                          written non-atomically to P[bx][81]  (ws)
//   stage2 <<<4,256>>>   : S[b][jf] = sum_r P rows; out = Acoeff . S / 810000

static __device__ __forceinline__ void add4(float4& a, const float4& b) {
    a.x += b.x; a.y += b.y; a.z += b.z; a.w += b.w;
}
static __device__ __forceinline__ void fma4(float4& a, float w, const float4& b) {
    a.x = fmaf(w, b.x, a.x); a.y = fmaf(w, b.y, a.y);
    a.z = fmaf(w, b.z, a.z); a.w = fmaf(w, b.w, a.w);
}

__global__ __launch_bounds__(256) void sdd4_stage0(
    const float* __restrict__ Mmat,     // [32,32]
    const float* __restrict__ Bbasis,   // [81,32]
    float* __restrict__ BM)             // [81,32]
{
    __shared__ float M_lds[32 * 33];
    const int t = threadIdx.x;          // 256 threads, 256 float4 in M
    {
        const float4* M4 = reinterpret_cast<const float4*>(Mmat);
        float4 v = M4[t];
        float* dst = &M_lds[(t >> 3) * 33 + (t & 7) * 4];
        dst[0] = v.x; dst[1] = v.y; dst[2] = v.z; dst[3] = v.w;
    }
    __syncthreads();
    // BM[j][m] = sum_n Bbasis[j][n] * M[n][m]   (2592 outputs)
    for (int o = t; o < 2592; o += 256) {
        const int j = o >> 5;
        const int m = o & 31;
        float acc = 0.f;
        #pragma unroll
        for (int n = 0; n < 32; ++n)
            acc = fmaf(Bbasis[j * 32 + n], M_lds[n * 33 + m], acc);
        BM[o] = acc;
    }
}

__global__ __launch_bounds__(128) void sdd4_stage1(
    const float* __restrict__ arr,
    const float* __restrict__ BM,       // [81,32] precomputed Bbasis@M
    float* __restrict__ P)              // [1024,81] per-block partials
{
    __shared__ float4 U_lds[400];       // [r*25 + cls*8 + mv]  (pad 24->25)
    __shared__ float  V_lds[9 * 33];    // [jj*33 + m]
    __shared__ float  BM_lds[81 * 33];  // [jf*33 + m]

    const int t  = threadIdx.x;
    const int bx = blockIdx.x;          // 0..1023
    const int b  = bx >> 8;
    const int p  = (bx >> 4) & 15;
    const int q  = bx & 15;

    // ---- stage BM (81x32) into padded LDS ----
    const float4* BM4 = reinterpret_cast<const float4*>(BM);
    for (int i = t; i < 648; i += 128) {
        float4 v = BM4[i];
        float* dst = &BM_lds[(i >> 3) * 33 + (i & 7) * 4];
        dst[0] = v.x; dst[1] = v.y; dst[2] = v.z; dst[3] = v.w;
    }

    // ---- main global read: tile arr[b,p,q,:,:,:], reduce over s per class ----
    const int r  = t >> 3;              // 0..15
    const int mv = t & 7;               // float4 index within m
    const float4* A4 = reinterpret_cast<const float4*>(arr);
    const size_t tile = (size_t)((b * 16 + p) * 16 + q) * 2048;

    float4 u0 = make_float4(0.f, 0.f, 0.f, 0.f), u1 = u0, u2 = u0;
    #pragma unroll
    for (int s = 0; s < 16; ++s) {
        float4 x = A4[tile + (size_t)(r * 16 + s) * 8 + mv];
        if ((0x36DBu >> s) & 1) add4(u0, x);
        if ((0x6DB6u >> s) & 1) add4(u1, x);
        if ((0xDB6Cu >> s) & 1) add4(u2, x);
    }
    U_lds[r * 25 +      mv] = u0;
    U_lds[r * 25 +  8 + mv] = u1;
    U_lds[r * 25 + 16 + mv] = u2;
    __syncthreads();

    // ---- reduce over r per class: V[j3][j4][m] ----
    if (t < 72) {
        const int j3  = t / 24;
        const int rem = t % 24;
        const int j4  = rem >> 3;
        const int mv2 = rem & 7;
        const unsigned msk = (j3 == 0) ? 0x36DBu : (j3 == 1 ? 0x6DB6u : 0xDB6Cu);
        float4 acc = make_float4(0.f, 0.f, 0.f, 0.f);
        #pragma unroll
        for (int rr = 0; rr < 16; ++rr) {
            float w = (float)((msk >> rr) & 1u);
            fma4(acc, w, U_lds[rr * 25 + j4 * 8 + mv2]);
        }
        const int jj = j3 * 3 + j4;
        float* dv = &V_lds[jj * 33 + mv2 * 4];
        dv[0] = acc.x; dv[1] = acc.y; dv[2] = acc.z; dv[3] = acc.w;
    }
    __syncthreads();

    // ---- all 81 jf: dot(BM[jf], V[jj]) if this (p,q) contributes, else 0 ----
    if (t < 81) {
        const int i1 = t / 27;
        const int i2 = (t / 9) % 3;
        const int jj = t % 9;
        const bool ok1 = (p == 0)  ? (i1 == 0)
                       : (p == 15) ? (i1 == 2)
                       : (i1 == (p - 1) % 3 || i1 == p % 3);
        const bool ok2 = (q == 0)  ? (i2 == 0)
                       : (q == 15) ? (i2 == 2)
                       : (i2 == (q - 1) % 3 || i2 == q % 3);
        float acc = 0.f;
        if (ok1 && ok2) {
            #pragma unroll
            for (int m = 0; m < 32; ++m)
                acc = fmaf(BM_lds[t * 33 + m], V_lds[jj * 33 + m], acc);
        }
        P[bx * 81 + t] = acc;   // non-atomic, disjoint rows
    }
}

__global__ __launch_bounds__(256) void sdd4_stage2(
    const float* __restrict__ P,        // [1024,81]
    const float* __restrict__ Acoeff,   // [32,81]
    float* __restrict__ out)            // [4,32]
{
    __shared__ float Sp[3 * 81];
    __shared__ float Sf[81];
    const int t = threadIdx.x;
    const int b = blockIdx.x;           // 0..3

    if (t < 243) {
        const int g  = t / 81;          // 0..2
        const int jf = t - g * 81;
        const float* base = P + (size_t)(b * 256) * 81 + jf;
        float acc = 0.f;
        #pragma unroll 4
        for (int r = g; r < 256; r += 3)
            acc += base[(size_t)r * 81];
        Sp[g * 81 + jf] = acc;
    }
    __syncthreads();
    if (t < 81) Sf[t] = Sp[t] + Sp[81 + t] + Sp[162 + t];
    __syncthreads();
    if (t < 32) {
        float acc = 0.f;
        #pragma unroll
        for (int j = 0; j < 81; ++j)
            acc = fmaf(Acoeff[t * 81 + j], Sf[j], acc);
        out[b * 32 + t] = acc * (1.0f / 810000.0f);   // 1/(16 * 15^4)
    }
}

extern "C" void kernel_launch(void* const* d_in, const int* in_sizes, int n_in,
                              void* d_out, int out_size, void* d_ws, size_t ws_size,
                              hipStream_t stream) {
    const float* arr    = (const float*)d_in[0];  // [4,16,16,16,16,32]
    const float* Mmat   = (const float*)d_in[1];  // [32,32]
    const float* Acoeff = (const float*)d_in[2];  // [32,81]
    const float* Bbasis = (const float*)d_in[3];  // [81,32]

    float* BM = (float*)d_ws;                     // 2592 floats
    float* P  = (float*)d_ws + 4096;              // 1024*81 floats (348 KB total ws)

    sdd4_stage0<<<dim3(1),    dim3(256), 0, stream>>>(Mmat, Bbasis, BM);
    sdd4_stage1<<<dim3(1024), dim3(128), 0, stream>>>(arr, BM, P);
    sdd4_stage2<<<dim3(4),    dim3(256), 0, stream>>>(P, Acoeff, (float*)d_out);
}

// Round 3
// 88.416 us; speedup vs baseline: 1.0636x; 1.0636x over previous
//
#include <hip/hip_runtime.h>

// out[b,n] = 1/(16*50625) * sum_j Acoeff[n,j] * S[b,j]
// S[b,j]   = sum_n Bbasis[j,n] * (M @ T[b,j])[n]
// T[b,j,m] = sum_{p,q,r,s} w[j1][p] w[j2][q] w[j3][r] w[j4][s] * arr[b,p,q,r,s,m]
// w masks (per dim, D=16, L=3, window R=2, stride 1, VALID):
//   class0: 0x36DB  class1: 0x6DB6  class2: 0xDB6C
//
// Single compute dispatch + 512B memset. The Acoeff application is linear, so
// each block folds its own <=36 combo contributions through Acoeff locally and
// atomicAdds a 32-float vector into out[b]. Device-scope atomics are the
// cross-XCD-safe primitive (plain loads across a grid barrier are NOT — R2
// failed on stale per-XCD L2 reads). No workspace, no stage2, no grid.sync.

static __device__ __forceinline__ void add4(float4& a, const float4& b) {
    a.x += b.x; a.y += b.y; a.z += b.z; a.w += b.w;
}
static __device__ __forceinline__ void fma4(float4& a, float w, const float4& b) {
    a.x = fmaf(w, b.x, a.x); a.y = fmaf(w, b.y, a.y);
    a.z = fmaf(w, b.z, a.z); a.w = fmaf(w, b.w, a.w);
}

__global__ __launch_bounds__(128) void sdd4_fused(
    const float* __restrict__ arr,      // [4,16,16,16,16,32]
    const float* __restrict__ Mmat,     // [32,32]
    const float* __restrict__ Bbasis,   // [81,32]
    const float* __restrict__ Acoeff,   // [32,81]
    float* __restrict__ out)            // [4,32], pre-zeroed
{
    __shared__ float4 U_lds[400];        // [r*25 + cls*8 + mv]  (pad 24->25)
    __shared__ float  V_lds[9 * 33];     // [jj*33 + m]
    __shared__ float  Y_lds[9 * 33];     // [jj*33 + n]
    __shared__ float  M_lds[32 * 33];    // [n*33 + m]
    __shared__ float  B_lds[81 * 33];    // [j*33 + n]
    __shared__ float  pv[36];            // per-combo dot results
    __shared__ int    jfv[36];           // per-combo flat j index

    const int t  = threadIdx.x;
    const int bx = blockIdx.x;           // 0..1023
    const int b  = bx >> 8;
    const int p  = (bx >> 4) & 15;
    const int q  = bx & 15;

    // ---- stage M (32x32) and Bbasis (81x32) into padded LDS ----
    const float4* M4 = reinterpret_cast<const float4*>(Mmat);
    for (int i = t; i < 256; i += 128) {
        float4 v = M4[i];
        float* dst = &M_lds[(i >> 3) * 33 + (i & 7) * 4];
        dst[0] = v.x; dst[1] = v.y; dst[2] = v.z; dst[3] = v.w;
    }
    const float4* B4 = reinterpret_cast<const float4*>(Bbasis);
    for (int i = t; i < 648; i += 128) {
        float4 v = B4[i];
        float* dst = &B_lds[(i >> 3) * 33 + (i & 7) * 4];
        dst[0] = v.x; dst[1] = v.y; dst[2] = v.z; dst[3] = v.w;
    }

    // ---- main global read: tile arr[b,p,q,:,:,:], reduce over s per class ----
    const int r  = t >> 3;               // 0..15
    const int mv = t & 7;                // float4 index within m
    const float4* A4 = reinterpret_cast<const float4*>(arr);
    const size_t tile = (size_t)((b * 16 + p) * 16 + q) * 2048;

    float4 u0 = make_float4(0.f, 0.f, 0.f, 0.f), u1 = u0, u2 = u0;
    #pragma unroll
    for (int s = 0; s < 16; ++s) {
        float4 x = A4[tile + (size_t)(r * 16 + s) * 8 + mv];
        if ((0x36DBu >> s) & 1) add4(u0, x);
        if ((0x6DB6u >> s) & 1) add4(u1, x);
        if ((0xDB6Cu >> s) & 1) add4(u2, x);
    }
    U_lds[r * 25 +      mv] = u0;
    U_lds[r * 25 +  8 + mv] = u1;
    U_lds[r * 25 + 16 + mv] = u2;
    __syncthreads();

    // ---- reduce over r per class: V[j3][j4][m] ----
    if (t < 72) {
        const int j3  = t / 24;
        const int rem = t % 24;
        const int j4  = rem >> 3;
        const int mv2 = rem & 7;
        const unsigned msk = (j3 == 0) ? 0x36DBu : (j3 == 1 ? 0x6DB6u : 0xDB6Cu);
        float4 acc = make_float4(0.f, 0.f, 0.f, 0.f);
        #pragma unroll
        for (int rr = 0; rr < 16; ++rr) {
            float w = (float)((msk >> rr) & 1u);
            fma4(acc, w, U_lds[rr * 25 + j4 * 8 + mv2]);
        }
        const int jj = j3 * 3 + j4;
        float* dv = &V_lds[jj * 33 + mv2 * 4];
        dv[0] = acc.x; dv[1] = acc.y; dv[2] = acc.z; dv[3] = acc.w;
    }
    __syncthreads();

    // ---- Y[jj][n] = sum_m M[n][m] * V[jj][m]   (9 matvecs of 32x32) ----
    for (int o = t; o < 288; o += 128) {
        const int jj = o >> 5;
        const int n  = o & 31;
        float acc = 0.f;
        #pragma unroll
        for (int m = 0; m < 32; ++m)
            acc = fmaf(M_lds[n * 33 + m], V_lds[jj * 33 + m], acc);
        Y_lds[jj * 33 + n] = acc;
    }
    __syncthreads();

    // ---- per-(j1,j2) combos for this (p,q): dot with Bbasis row ----
    int l1_0, l1_1 = 0, n1;
    if      (p == 0)  { l1_0 = 0; n1 = 1; }
    else if (p == 15) { l1_0 = 2; n1 = 1; }
    else              { l1_0 = (p - 1) % 3; l1_1 = p % 3; n1 = 2; }
    int l2_0, l2_1 = 0, n2;
    if      (q == 0)  { l2_0 = 0; n2 = 1; }
    else if (q == 15) { l2_0 = 2; n2 = 1; }
    else              { l2_0 = (q - 1) % 3; l2_1 = q % 3; n2 = 2; }

    const int ncomb = n1 * n2 * 9;
    if (t < ncomb) {
        const int jj  = t % 9;           // j3*3 + j4
        const int c12 = t / 9;
        const int i1idx = (n2 == 2) ? (c12 >> 1) : c12;
        const int i2idx = (n2 == 2) ? (c12 & 1)  : 0;
        const int i1 = i1idx ? l1_1 : l1_0;
        const int i2 = i2idx ? l2_1 : l2_0;
        const int jf = (i1 * 3 + i2) * 9 + jj;
        float acc = 0.f;
        #pragma unroll
        for (int n = 0; n < 32; ++n)
            acc = fmaf(Y_lds[jj * 33 + n], B_lds[jf * 33 + n], acc);
        pv[t]  = acc;
        jfv[t] = jf;
    }
    __syncthreads();

    // ---- fold through Acoeff locally, one atomicAdd vector per block ----
    if (t < 32) {
        float acc = 0.f;
        for (int c = 0; c < ncomb; ++c)
            acc = fmaf(Acoeff[t * 81 + jfv[c]], pv[c], acc);
        atomicAdd(&out[b * 32 + t], acc * (1.0f / 810000.0f)); // 1/(16*15^4)
    }
}

extern "C" void kernel_launch(void* const* d_in, const int* in_sizes, int n_in,
                              void* d_out, int out_size, void* d_ws, size_t ws_size,
                              hipStream_t stream) {
    const float* arr    = (const float*)d_in[0];  // [4,16,16,16,16,32]
    const float* Mmat   = (const float*)d_in[1];  // [32,32]
    const float* Acoeff = (const float*)d_in[2];  // [32,81]
    const float* Bbasis = (const float*)d_in[3];  // [81,32]

    hipMemsetAsync(d_out, 0, 4 * 32 * sizeof(float), stream);
    sdd4_fused<<<dim3(1024), dim3(128), 0, stream>>>(arr, Mmat, Bbasis, Acoeff,
                                                     (float*)d_out);
}